// Round 6
// baseline (148.034 us; speedup 1.0000x reference)
//
#include <hip/hip_runtime.h>

#define NUM_GRAPHS 512
#define NPG 200      // nodes per graph
#define EPG 3200     // edges per graph
#define NROIS 200    // input feature dim
#define HID 64
#define OUTC 2
#define APITCH 232   // adjacency row pitch (bytes) = 58 dw
#define HPITCH 232   // hpTl row pitch (elements); 464 B = 29*16 -> b128-aligned rows
#define WIMG_ELEMS (7 * 4 * 2 * 64 * 8)   // 28672 ushorts (W hi/lo frag image)
#define WS_NEEDED ((size_t)WIMG_ELEMS * 2)

typedef short v8s __attribute__((ext_vector_type(8)));
typedef float v4f __attribute__((ext_vector_type(4)));

__device__ __forceinline__ unsigned bf16_rne(float f) {
  unsigned u = __float_as_uint(f);
  return (u + 0x7fffu + ((u >> 16) & 1u)) >> 16;
}

// ============ prep: W -> bf16 hi/lo fragment-order image ============
__global__ void prep_wimg(const float* __restrict__ cw, unsigned short* __restrict__ wimg) {
  int idx = blockIdx.x * 256 + threadIdx.x;
  if (idx >= WIMG_ELEMS) return;
  int i    = idx & 7;
  int lane = (idx >> 3) & 63;
  int hl   = (idx >> 9) & 1;
  int nt   = (idx >> 10) & 3;
  int kt   = idx >> 12;
  int k  = kt * 32 + (lane >> 4) * 8 + i;
  int ch = nt * 16 + (lane & 15);
  float f = (k < NROIS) ? cw[k * HID + ch] : 0.f;
  unsigned hi = bf16_rne(f);
  float lo = f - __uint_as_float(hi << 16);
  wimg[idx] = hl ? (unsigned short)(__float_as_uint(lo) >> 16) : (unsigned short)hi;
}

// ============ fused kernel v9 ============
// v8 + GEMM1 re-pipelined: 2-kt macro-iterations, 4-tile W LDS ring, counted
// s_waitcnt vmcnt(N) + raw s_barrier (waits own W-DMAs ONLY; deep x prefetches
// stay in flight ACROSS barriers). In-loop full drains 7 -> 3. Numerics
// identical to v8 (same values, same MFMA order).
// LDS: 46400 (adj, 200 rows) + 32768 (hpTl | wbuf4) + 800 + 800 + 256
//    = 81024 B <= 81920 -> 2 blocks/CU (16 waves).
struct __align__(16) Smem2 {
  unsigned char adj[200 * APITCH];        // (A+I) counts as bytes
  union {
    unsigned short hpTl[HID * HPITCH];    // bf16 dinv[src]*h[src][ch] (post-GEMM1)
    unsigned int wbuf4[4][2048];          // 4 x 8KB W-tile ring (GEMM1); slot = kt&3
  } u;
  int cnt[NPG];                           // in-degree (edges only; +1 for self-loop)
  float dinv[NPG];
  int pool[HID];
};

__device__ __forceinline__ v8s tobf16(const float4& a, const float4& b) {
  v8s r;
  r[0] = (short)bf16_rne(a.x); r[1] = (short)bf16_rne(a.y);
  r[2] = (short)bf16_rne(a.z); r[3] = (short)bf16_rne(a.w);
  r[4] = (short)bf16_rne(b.x); r[5] = (short)bf16_rne(b.y);
  r[6] = (short)bf16_rne(b.z); r[7] = (short)bf16_rne(b.w);
  return r;
}

// DMA W tile t (8KB) into ring slot t&3: each thread one 16B chunk.
__device__ __forceinline__ void stageW4(Smem2& s, const unsigned short* __restrict__ wimg,
                                        int t, int w, int lane) {
  const char* gp = (const char*)wimg + (size_t)t * 8192 + (size_t)(w * 64 + lane) * 16;
  unsigned char* lp = (unsigned char*)&s.u.wbuf4[t & 3][0] + w * 1024;
  __builtin_amdgcn_global_load_lds(
      (const __attribute__((address_space(1))) unsigned int*)gp,
      (__attribute__((address_space(3))) unsigned int*)lp, 16, 0, 0);
}

// x fragment loads for K-tile kt into ring slot: lane reads 8 consecutive floats
// x[node][kt*32 + q*8 ..). kt=6,q>=1 runs past col 200 -> zero-fill.
__device__ __forceinline__ void xfetch(const float* __restrict__ x, int base,
                                       int kt, int q, const int* mts, const int* nrow,
                                       float4 xa[2][2]) {
  const int k0 = kt * 32 + q * 8;
  const bool ok = (k0 + 8 <= NROIS);
  #pragma unroll
  for (int mi = 0; mi < 2; ++mi) {
    if (mts[mi] >= 0) {
      if (ok) {
        const float* px = x + (size_t)(base + nrow[mi]) * NROIS + k0;
        xa[mi][0] = *(const float4*)px;
        xa[mi][1] = *(const float4*)(px + 4);
      } else {
        xa[mi][0] = make_float4(0.f, 0.f, 0.f, 0.f);
        xa[mi][1] = make_float4(0.f, 0.f, 0.f, 0.f);
      }
    }
  }
}

// one kt of GEMM1: convert x slot SL, read W slot KT&3 from LDS, 16 MFMAs.
template<int KT, int SL>
__device__ __forceinline__ void kt_step(Smem2& s, float4 (&xa)[3][2][2],
                                        v4f (&acc)[2][4], const int* mts, int lane) {
  v8s xh2[2];
  #pragma unroll
  for (int mi = 0; mi < 2; ++mi)
    if (mts[mi] >= 0) xh2[mi] = tobf16(xa[SL][mi][0], xa[SL][mi][1]);
  const unsigned short* wb = (const unsigned short*)&s.u.wbuf4[KT & 3][0];
  v8s whi[4], wlo[4];
  #pragma unroll
  for (int nt = 0; nt < 4; ++nt) {
    whi[nt] = *(const v8s*)(wb + (size_t)((nt * 2 + 0) * 64 + lane) * 8);
    wlo[nt] = *(const v8s*)(wb + (size_t)((nt * 2 + 1) * 64 + lane) * 8);
  }
  #pragma unroll
  for (int mi = 0; mi < 2; ++mi) {
    if (mts[mi] >= 0) {
      #pragma unroll
      for (int nt = 0; nt < 4; ++nt) {
        acc[mi][nt] = __builtin_amdgcn_mfma_f32_16x16x32_bf16(wlo[nt], xh2[mi], acc[mi][nt], 0, 0, 0);
        acc[mi][nt] = __builtin_amdgcn_mfma_f32_16x16x32_bf16(whi[nt], xh2[mi], acc[mi][nt], 0, 0, 0);
      }
    }
  }
}

// counted-vmcnt barrier: waits this wave's W-DMAs (leaves the N newest x loads
// in flight), then rendezvous. lgkmcnt(0) covers ds ordering (cheap).
#define WAITBAR(N) asm volatile("s_waitcnt vmcnt(" #N ") lgkmcnt(0)\n\ts_barrier" ::: "memory")

__global__ __launch_bounds__(512, 4)
void gcn_fused9(const float* __restrict__ x,
                const int* __restrict__ ei,
                const unsigned short* __restrict__ wimg,
                const float* __restrict__ cb,
                const float* __restrict__ lw,
                const float* __restrict__ lb,
                float* __restrict__ out,
                int Etot) {
  __shared__ Smem2 s;
  const int g = blockIdx.x;
  const int tid = threadIdx.x;
  const int base = g * NPG;
  const int ebase = g * EPG;
  const int lane = tid & 63;
  const int w = __builtin_amdgcn_readfirstlane(tid >> 6);  // 0..7
  const int ml = tid & 15;
  const int q  = (tid >> 4) & 3;

  int mts[2];
  mts[0] = w;
  mts[1] = (w < 5) ? 8 + w : -1;
  int nrow[2];                       // clamped row index for x loads (junk discarded)
  #pragma unroll
  for (int mi = 0; mi < 2; ++mi) {
    int node = mts[mi] * 16 + ml;
    nrow[mi] = (node < NPG) ? node : 0;
  }

  // ---- startup: x tiles 0-2, W tiles 0-1 DMA, edge loads; zero adj/cnt/pool ----
  float4 xa[3][2][2];
  xfetch(x, base, 0, q, mts, nrow, xa[0]);
  xfetch(x, base, 1, q, mts, nrow, xa[1]);
  xfetch(x, base, 2, q, mts, nrow, xa[2]);
  stageW4(s, wimg, 0, w, lane);
  stageW4(s, wimg, 1, w, lane);
  int esrc[7], edst[7];
  #pragma unroll
  for (int r = 0; r < 7; ++r) {
    int e = tid + r * 512;
    esrc[r] = -1; edst[r] = 0;
    if (e < EPG) {
      esrc[r] = ei[ebase + e] - base;
      edst[r] = ei[Etot + ebase + e] - base;
    }
  }
  {
    uint4* z = (uint4*)s.adj;
    const uint4 z4 = {0u, 0u, 0u, 0u};
    #pragma unroll
    for (int i = 0; i < 6; ++i) {
      int idx = tid + i * 512;
      if (idx < (200 * APITCH) / 16) z[idx] = z4;
    }
    if (tid < NPG) s.cnt[tid] = 0;
    if (tid < HID) s.pool[tid] = 0;   // relu >= 0 -> 0 is identity for max
  }
  __syncthreads();   // zeroes visible; x0-2/W0-1/edges drained (full drain, startup)

  // ---- scatter (A+I) counts + in-degree (fire-and-forget ds atomics; drain
  //      at the in-loop barriers, long before adj/cnt are read) ----
  {
    unsigned* adjW = (unsigned*)s.adj;
    #pragma unroll
    for (int r = 0; r < 7; ++r) {
      if (esrc[r] >= 0) {
        int idx = edst[r] * APITCH + esrc[r];
        atomicAdd(&adjW[idx >> 2], 1u << ((idx & 3) * 8));
        atomicAdd(&s.cnt[edst[r]], 1);
      }
    }
    if (tid < NPG) {                      // self-loop diagonal (degree = cnt+1)
      int idx = tid * APITCH + tid;
      atomicAdd(&adjW[idx >> 2], 1u << ((idx & 3) * 8));
    }
  }

  // ---- GEMM1: H = X @ W, 2-kt macro-iterations, counted-vmcnt barriers ----
  v4f acc[2][4];
  #pragma unroll
  for (int a = 0; a < 2; ++a)
    #pragma unroll
    for (int b = 0; b < 4; ++b)
      acc[a][b] = (v4f){0.f, 0.f, 0.f, 0.f};

  // mt0: compute kt0,kt1 (W slots 0,1); DMA tiles 2,3; prefetch x3,x4
  stageW4(s, wimg, 2, w, lane);
  stageW4(s, wimg, 3, w, lane);
  kt_step<0, 0>(s, xa, acc, mts, lane);
  kt_step<1, 1>(s, xa, acc, mts, lane);
  xfetch(x, base, 3, q, mts, nrow, xa[0]);
  xfetch(x, base, 4, q, mts, nrow, xa[1]);
  if (w < 5) WAITBAR(8); else WAITBAR(4);   // own DMAs done; x3,x4 stay in flight

  // mt1: compute kt2,kt3 (W slots 2,3); DMA tiles 4,5 (slots 0,1); prefetch x5,x6
  stageW4(s, wimg, 4, w, lane);
  stageW4(s, wimg, 5, w, lane);
  kt_step<2, 2>(s, xa, acc, mts, lane);
  kt_step<3, 0>(s, xa, acc, mts, lane);
  xfetch(x, base, 5, q, mts, nrow, xa[2]);
  xfetch(x, base, 6, q, mts, nrow, xa[0]);
  if (w < 5) WAITBAR(8); else WAITBAR(4);   // x5,x6 stay in flight

  // mt2: compute kt4,kt5 (W slots 0,1); DMA tile 6 (slot 2)
  stageW4(s, wimg, 6, w, lane);
  kt_step<4, 1>(s, xa, acc, mts, lane);
  kt_step<5, 2>(s, xa, acc, mts, lane);
  WAITBAR(0);                                // drain DMA6 (+x6, consumed next)

  // kt6 (W slot 2)
  kt_step<6, 0>(s, xa, acc, mts, lane);
  __syncthreads();    // scatter + cnt complete, GEMM1 accs final, wbuf dead

  // ---- dinv table + pad-zero hpTl cols [200,232) + epilogue1 ----
  if (tid < NPG) s.dinv[tid] = rsqrtf((float)(s.cnt[tid] + 1));
  {
    int ch = tid >> 3, grp = tid & 7;
    *(uint2*)&s.u.hpTl[ch * HPITCH + 200 + grp * 4] = (uint2){0u, 0u};
  }
  #pragma unroll
  for (int mi = 0; mi < 2; ++mi) {
    if (mts[mi] >= 0) {
      const int node = mts[mi] * 16 + ml;
      if (node < NPG) {
        const float dv = rsqrtf((float)(s.cnt[node] + 1));   // bitwise == s.dinv[node]
        #pragma unroll
        for (int nt = 0; nt < 4; ++nt) {
          #pragma unroll
          for (int r = 0; r < 4; ++r) {
            const int ch = nt * 16 + q * 4 + r;
            s.u.hpTl[ch * HPITCH + node] = (unsigned short)bf16_rne(dv * acc[mi][nt][r]);
          }
        }
      }
    }
  }
  __syncthreads();

  // ---- GEMM2: AGG = (A+I) @ hp (counts exact in bf16) ----
  {
    v4f acc2[2][4];
    #pragma unroll
    for (int a = 0; a < 2; ++a)
      #pragma unroll
      for (int b = 0; b < 4; ++b)
        acc2[a][b] = (v4f){0.f, 0.f, 0.f, 0.f};

    for (int kt = 0; kt < 7; ++kt) {
      const int k0 = kt * 32 + q * 8;

      v8s bf[4];
      #pragma unroll
      for (int nt = 0; nt < 4; ++nt)
        bf[nt] = *(const v8s*)&s.u.hpTl[(nt * 16 + ml) * HPITCH + k0];

      #pragma unroll
      for (int mi = 0; mi < 2; ++mi) {
        if (mts[mi] >= 0) {
          const int row = mts[mi] * 16 + ml;
          const int arow = (row < NPG) ? row : 0;     // adj has 200 rows now
          const uint2 dd = *(const uint2*)&s.adj[arow * APITCH + k0];
          v8s af;
          #pragma unroll
          for (int i = 0; i < 4; ++i) {
            af[i]     = (short)(__float_as_uint((float)((dd.x >> (8 * i)) & 0xffu)) >> 16);
            af[i + 4] = (short)(__float_as_uint((float)((dd.y >> (8 * i)) & 0xffu)) >> 16);
          }
          #pragma unroll
          for (int nt = 0; nt < 4; ++nt)
            acc2[mi][nt] = __builtin_amdgcn_mfma_f32_16x16x32_bf16(af, bf[nt], acc2[mi][nt], 0, 0, 0);
        }
      }
    }

    // epilogue2: relu(dinv[dst]*agg + cb) -> max-pool
    float cbv[4];
    #pragma unroll
    for (int nt = 0; nt < 4; ++nt) cbv[nt] = cb[nt * 16 + ml];
    float mx[4] = {0.f, 0.f, 0.f, 0.f};
    #pragma unroll
    for (int mi = 0; mi < 2; ++mi) {
      if (mts[mi] >= 0) {
        #pragma unroll
        for (int r = 0; r < 4; ++r) {
          const int row = mts[mi] * 16 + q * 4 + r;
          if (row < NPG) {
            const float dv = s.dinv[row];
            #pragma unroll
            for (int nt = 0; nt < 4; ++nt) {
              float v = fmaxf(fmaf(dv, acc2[mi][nt][r], cbv[nt]), 0.f);
              mx[nt] = fmaxf(mx[nt], v);
            }
          }
        }
      }
    }
    #pragma unroll
    for (int nt = 0; nt < 4; ++nt) {
      mx[nt] = fmaxf(mx[nt], __shfl_xor(mx[nt], 16));
      mx[nt] = fmaxf(mx[nt], __shfl_xor(mx[nt], 32));
    }
    if (q == 0 && (lane >> 5) == 0) {
      #pragma unroll
      for (int nt = 0; nt < 4; ++nt)
        atomicMax(&s.pool[nt * 16 + ml], __float_as_int(mx[nt]));
    }
  }
  __syncthreads();

  // ---- write x_pool and out ----
  if (tid < HID) {
    const float xp = __int_as_float(s.pool[tid]);
    out[NUM_GRAPHS * OUTC + g * HID + tid] = xp;
    float p0 = xp * lw[tid * 2 + 0];
    float p1 = xp * lw[tid * 2 + 1];
    #pragma unroll
    for (int off = 32; off > 0; off >>= 1) {
      p0 += __shfl_down(p0, off);
      p1 += __shfl_down(p1, off);
    }
    if (tid == 0) {
      out[g * OUTC + 0] = p0 + lb[0];
      out[g * OUTC + 1] = p1 + lb[1];
    }
  }
}

// ============ fallback (ws too small): fused kernel, inline W convert ============
struct __align__(16) SmemF {
  unsigned char adj[208 * APITCH];
  unsigned short hpT[HID * HPITCH];
  float dinv[NPG];
  int cnt[NPG];
  int pool[HID];
};

__global__ __launch_bounds__(512, 4)
void gcn_fused_fb(const float* __restrict__ x,
                  const int* __restrict__ ei,
                  const float* __restrict__ cw,
                  const float* __restrict__ cb,
                  const float* __restrict__ lw,
                  const float* __restrict__ lb,
                  float* __restrict__ out,
                  int Etot) {
  __shared__ SmemF s;
  const int g = blockIdx.x;
  const int tid = threadIdx.x;
  const int base = g * NPG;
  const int ebase = g * EPG;
  const int lane = tid & 63;
  const int w = __builtin_amdgcn_readfirstlane(tid >> 6);
  const int ml = tid & 15;
  const int q  = (tid >> 4) & 3;

  {
    uint4* z = (uint4*)&s;
    const uint4 z4 = {0u, 0u, 0u, 0u};
    #pragma unroll
    for (int i = 0; i < 10; ++i) {
      int idx = tid + i * 512;
      if (idx < (208 * APITCH + HID * HPITCH * 2) / 16) z[idx] = z4;
    }
    if (tid < NPG) s.cnt[tid] = 0;
    if (tid < HID) s.pool[tid] = 0;
  }
  __syncthreads();

  int esrc[7], edst[7];
  #pragma unroll
  for (int r = 0; r < 7; ++r) {
    int e = tid + r * 512;
    esrc[r] = -1; edst[r] = 0;
    if (e < EPG) {
      esrc[r] = ei[ebase + e] - base;
      edst[r] = ei[Etot + ebase + e] - base;
      atomicAdd(&s.cnt[edst[r]], 1);
    }
  }
  __syncthreads();

  if (tid < NPG) s.dinv[tid] = rsqrtf((float)(s.cnt[tid] + 1));

  {
    unsigned* adjW = (unsigned*)s.adj;
    #pragma unroll
    for (int r = 0; r < 7; ++r) {
      if (esrc[r] >= 0) {
        int idx = edst[r] * APITCH + esrc[r];
        atomicAdd(&adjW[idx >> 2], 1u << ((idx & 3) * 8));
      }
    }
    if (tid < NPG) {
      int idx = tid * APITCH + tid;
      atomicAdd(&adjW[idx >> 2], 1u << ((idx & 3) * 8));
    }
  }
  __syncthreads();

  {
    int mts[2];
    mts[0] = w;
    mts[1] = (w < 5) ? 8 + w : -1;
    v4f acc[2][4];
    #pragma unroll
    for (int a = 0; a < 2; ++a)
      #pragma unroll
      for (int b = 0; b < 4; ++b)
        acc[a][b] = (v4f){0.f, 0.f, 0.f, 0.f};

    for (int kt = 0; kt < 7; ++kt) {
      const int k0 = kt * 32 + q * 8;
      const bool kok = (k0 < NROIS);
      v8s bhi[4], blo[4];
      #pragma unroll
      for (int nt = 0; nt < 4; ++nt) {
        #pragma unroll
        for (int i = 0; i < 8; ++i) {
          float f = kok ? cw[(k0 + i) * HID + nt * 16 + ml] : 0.f;
          unsigned hb = bf16_rne(f);
          float lo = f - __uint_as_float(hb << 16);
          bhi[nt][i] = (short)hb;
          blo[nt][i] = (short)(__float_as_uint(lo) >> 16);
        }
      }
      #pragma unroll
      for (int mi = 0; mi < 2; ++mi) {
        if (mts[mi] >= 0) {
          const int row = mts[mi] * 16 + ml;
          v8s ahi, alo;
          if (kok && row < NPG) {
            const float* px = x + (size_t)(base + row) * NROIS + k0;
            const float4 f0 = *(const float4*)px;
            const float4 f1 = *(const float4*)(px + 4);
            const float ff[8] = {f0.x, f0.y, f0.z, f0.w, f1.x, f1.y, f1.z, f1.w};
            #pragma unroll
            for (int i = 0; i < 8; ++i) {
              unsigned u = __float_as_uint(ff[i]);
              unsigned hb = u >> 16;
              float lo = ff[i] - __uint_as_float(hb << 16);
              ahi[i] = (short)hb;
              alo[i] = (short)(__float_as_uint(lo) >> 16);
            }
          } else {
            #pragma unroll
            for (int i = 0; i < 8; ++i) { ahi[i] = 0; alo[i] = 0; }
          }
          #pragma unroll
          for (int nt = 0; nt < 4; ++nt) {
            acc[mi][nt] = __builtin_amdgcn_mfma_f32_16x16x32_bf16(ahi, blo[nt], acc[mi][nt], 0, 0, 0);
            acc[mi][nt] = __builtin_amdgcn_mfma_f32_16x16x32_bf16(alo, bhi[nt], acc[mi][nt], 0, 0, 0);
            acc[mi][nt] = __builtin_amdgcn_mfma_f32_16x16x32_bf16(ahi, bhi[nt], acc[mi][nt], 0, 0, 0);
          }
        }
      }
    }
    #pragma unroll
    for (int mi = 0; mi < 2; ++mi) {
      if (mts[mi] >= 0) {
        #pragma unroll
        for (int r = 0; r < 4; ++r) {
          const int row = mts[mi] * 16 + q * 4 + r;
          if (row < NPG) {
            const float dv = s.dinv[row];
            #pragma unroll
            for (int nt = 0; nt < 4; ++nt)
              s.hpT[(nt * 16 + ml) * HPITCH + row] =
                  (unsigned short)bf16_rne(dv * acc[mi][nt][r]);
          }
        }
      }
    }
  }
  __syncthreads();

  {
    int mts[2];
    mts[0] = w;
    mts[1] = (w < 5) ? 8 + w : -1;
    v4f acc2[2][4];
    #pragma unroll
    for (int a = 0; a < 2; ++a)
      #pragma unroll
      for (int b = 0; b < 4; ++b)
        acc2[a][b] = (v4f){0.f, 0.f, 0.f, 0.f};

    for (int kt = 0; kt < 7; ++kt) {
      const int k0 = kt * 32 + q * 8;
      v8s bf[4];
      #pragma unroll
      for (int nt = 0; nt < 4; ++nt)
        bf[nt] = *(const v8s*)&s.hpT[(nt * 16 + ml) * HPITCH + k0];
      #pragma unroll
      for (int mi = 0; mi < 2; ++mi) {
        if (mts[mi] >= 0) {
          const int row = mts[mi] * 16 + ml;
          const uint2 dd = *(const uint2*)&s.adj[row * APITCH + k0];
          v8s af;
          #pragma unroll
          for (int i = 0; i < 4; ++i) {
            af[i]     = (short)(__float_as_uint((float)((dd.x >> (8 * i)) & 0xffu)) >> 16);
            af[i + 4] = (short)(__float_as_uint((float)((dd.y >> (8 * i)) & 0xffu)) >> 16);
          }
          #pragma unroll
          for (int nt = 0; nt < 4; ++nt)
            acc2[mi][nt] = __builtin_amdgcn_mfma_f32_16x16x32_bf16(af, bf[nt], acc2[mi][nt], 0, 0, 0);
        }
      }
    }

    float cbv[4];
    #pragma unroll
    for (int nt = 0; nt < 4; ++nt) cbv[nt] = cb[nt * 16 + ml];
    float mx[4] = {0.f, 0.f, 0.f, 0.f};
    #pragma unroll
    for (int mi = 0; mi < 2; ++mi) {
      if (mts[mi] >= 0) {
        #pragma unroll
        for (int r = 0; r < 4; ++r) {
          const int row = mts[mi] * 16 + q * 4 + r;
          if (row < NPG) {
            const float dv = s.dinv[row];
            #pragma unroll
            for (int nt = 0; nt < 4; ++nt) {
              float v = fmaxf(fmaf(dv, acc2[mi][nt][r], cbv[nt]), 0.f);
              mx[nt] = fmaxf(mx[nt], v);
            }
          }
        }
      }
    }
    #pragma unroll
    for (int nt = 0; nt < 4; ++nt) {
      mx[nt] = fmaxf(mx[nt], __shfl_xor(mx[nt], 16));
      mx[nt] = fmaxf(mx[nt], __shfl_xor(mx[nt], 32));
    }
    if (q == 0 && (lane >> 5) == 0) {
      #pragma unroll
      for (int nt = 0; nt < 4; ++nt)
        atomicMax(&s.pool[nt * 16 + ml], __float_as_int(mx[nt]));
    }
  }
  __syncthreads();

  if (tid < HID) {
    const float xp = __int_as_float(s.pool[tid]);
    out[NUM_GRAPHS * OUTC + g * HID + tid] = xp;
    float p0 = xp * lw[tid * 2 + 0];
    float p1 = xp * lw[tid * 2 + 1];
    #pragma unroll
    for (int off = 32; off > 0; off >>= 1) {
      p0 += __shfl_down(p0, off);
      p1 += __shfl_down(p1, off);
    }
    if (tid == 0) {
      out[g * OUTC + 0] = p0 + lb[0];
      out[g * OUTC + 1] = p1 + lb[1];
    }
  }
}

extern "C" void kernel_launch(void* const* d_in, const int* in_sizes, int n_in,
                              void* d_out, int out_size, void* d_ws, size_t ws_size,
                              hipStream_t stream) {
  const float* x  = (const float*)d_in[0];
  const int*   ei = (const int*)d_in[1];
  // d_in[2] = batch (node/200 by construction; unused)
  const float* cw = (const float*)d_in[3];
  const float* cb = (const float*)d_in[4];
  const float* lw = (const float*)d_in[5];
  const float* lb = (const float*)d_in[6];
  const int Etot = in_sizes[1] / 2;

  if (ws_size >= WS_NEEDED) {
    unsigned short* wimg = (unsigned short*)d_ws;
    prep_wimg<<<(WIMG_ELEMS + 255) / 256, 256, 0, stream>>>(cw, wimg);
    gcn_fused9<<<NUM_GRAPHS, 512, 0, stream>>>(x, ei, wimg, cb, lw, lb,
                                               (float*)d_out, Etot);
  } else {
    gcn_fused_fb<<<NUM_GRAPHS, 512, 0, stream>>>(x, ei, cw, cb, lw, lb,
                                                 (float*)d_out, Etot);
  }
}